// Round 11
// baseline (144.294 us; speedup 1.0000x reference)
//
#include <hip/hip_runtime.h>
#include <math.h>

// Problem constants (reference: B=2, S=T=400, D=512)
#define BB 2
#define SS 400
#define DD 512
#define TWO_LOG2E 2.8853900817779268f

#if __has_builtin(__builtin_amdgcn_exp2f)
#define EXP2F(x) __builtin_amdgcn_exp2f(x)
#else
#define EXP2F(x) exp2f(x)
#endif
#define RCPF(x) __builtin_amdgcn_rcpf(x)

// Workspace float layout:
//   Ea   [0,       409600) : exp2(2L*(input@Wq + bq))            [B,T,D]
//   M    [409600,  819200) : mb@Wout_top                         [B,S,D]
//   Eb4  [819200, 1228800) : exp2(2L*(mb@Wc)), packed [B][D/4][S][4]
//   X    [1228800, 2572288) : bf16 staging (shorts):
//        wt  [0,        1048576) : Wt [g][1024][512]
//        ahi [1048576,  1458176) : hi(A) [g][800][512]
//        alo [1458176,  1867776) : lo(A) [g][800][512]
//   Sp   [2572288, 3391488) : score partials [eh][b][t][512]
// out0 gets input@Wout_bot + bout from k1 (g0 cols>=512); k2b phase-2 adds
// align@M in-block (non-atomic, each (t,b) owned by exactly one block).
#define EAOFF 0
#define MOFF 409600
#define EB4OFF 819200
#define XOFF 1228800
#define SPOFF 2572288

typedef __bf16 bf16x8 __attribute__((ext_vector_type(8)));
typedef float floatx16 __attribute__((ext_vector_type(16)));

// ---------------------------------------------------------------------------
// K0: fused prep. Flat grid 1824 blocks, 256 thr.
//  gid < 1024: Wt[g][n][k] bf16 transpose-pack (32x32 LDS tiles).
//  gid >= 1024: two-term bf16 split of A (input / mb).
// ---------------------------------------------------------------------------
__global__ __launch_bounds__(256) void k0_all(
    const float* __restrict__ Wq, const float* __restrict__ Wc,
    const float* __restrict__ Wout, const float* __restrict__ input,
    const float* __restrict__ mbk, unsigned short* __restrict__ wt,
    unsigned short* __restrict__ ahi, unsigned short* __restrict__ alo)
{
    const int gid = blockIdx.x;
    if (gid < 1024) {
        const int g   = gid >> 9;
        const int rem = gid & 511;
        const int k0  = (rem & 15) * 32;
        const int n0  = (rem >> 4) * 32;

        __shared__ float tile[32][33];
        const int nn  = threadIdx.x & 31;
        const int kk0 = threadIdx.x >> 5;
        const int n   = n0 + nn;

        #pragma unroll
        for (int p = 0; p < 4; ++p) {
            const int k = k0 + kk0 + p * 8;
            float val;
            if (n0 < 512) val = (g ? Wc : Wq)[(size_t)k * 512 + n];
            else          val = Wout[((size_t)(g ? k : 512 + k)) * 512 + (n - 512)];
            tile[kk0 + p * 8][nn] = val;
        }
        __syncthreads();

        const int kc = threadIdx.x & 31;
        #pragma unroll
        for (int p = 0; p < 4; ++p) {
            const int nl = (threadIdx.x >> 5) + p * 8;
            const __bf16 h = (__bf16)tile[kc][nl];
            wt[((size_t)(g * 1024 + n0 + nl)) * 512 + k0 + kc] =
                __builtin_bit_cast(unsigned short, h);
        }
    } else {
        const int cid = gid - 1024;             // 0..799
        const int g   = (cid >= 400) ? 1 : 0;
        const int i4  = (cid - g * 400) * 256 + threadIdx.x;   // 0..102399
        const float4 a = ((const float4*)(g ? mbk : input))[i4];
        ushort4 h, l;
        #pragma unroll
        for (int j = 0; j < 4; ++j) {
            const float av = (&a.x)[j];
            const __bf16 hh = (__bf16)av;
            (&h.x)[j] = __builtin_bit_cast(unsigned short, hh);
            const __bf16 ll = (__bf16)(av - (float)hh);
            (&l.x)[j] = __builtin_bit_cast(unsigned short, ll);
        }
        ((ushort4*)(ahi + (size_t)g * 409600))[i4] = h;
        ((ushort4*)(alo + (size_t)g * 409600))[i4] = l;
    }
}

// ---------------------------------------------------------------------------
// K1: two merged GEMMs (800 x 1024 x 512) via MFMA, pre-split bf16 A.
// Grid (25 mtiles, 16 npairs, 2 g), 64 thr = 1 wave; wave tile 32x64.
// C/D: col=lane&31, row=(reg&3)+8*(reg>>2)+4*(lane>>5).
// Fused epilogues by n-range/g: Ea, out0(=P+bout), Eb4 scatter, M.
// ---------------------------------------------------------------------------
__global__ __launch_bounds__(64) void k1_mfma(
    const unsigned short* __restrict__ ahi, const unsigned short* __restrict__ alo,
    const unsigned short* __restrict__ wt, const float* __restrict__ bq,
    const float* __restrict__ bout, float* __restrict__ ws,
    float* __restrict__ out0)
{
    const int lane = threadIdx.x;
    const int mt   = blockIdx.x;          // 0..24
    const int np   = blockIdx.y;          // 0..15
    const int g    = blockIdx.z;
    const int m    = lane & 31;
    const int kh   = lane >> 5;
    const int n0   = np * 64;

    const size_t arow = ((size_t)g * 800 + mt * 32 + m) * 512 + kh * 8;
    const unsigned short* __restrict__ ah = ahi + arow;
    const unsigned short* __restrict__ al = alo + arow;
    const unsigned short* __restrict__ w0 =
        wt + ((size_t)(g * 1024 + n0 + m)) * 512 + kh * 8;
    const unsigned short* __restrict__ w1 = w0 + (size_t)32 * 512;

    floatx16 acc0h, acc0l, acc1h, acc1l;
    #pragma unroll
    for (int i = 0; i < 16; ++i) { acc0h[i] = 0.f; acc0l[i] = 0.f;
                                   acc1h[i] = 0.f; acc1l[i] = 0.f; }

    #pragma unroll 4
    for (int ks = 0; ks < 32; ++ks) {
        const bf16x8 va0 = *(const bf16x8*)(ah + ks * 16);
        const bf16x8 va1 = *(const bf16x8*)(al + ks * 16);
        const bf16x8 bh0 = *(const bf16x8*)(w0 + ks * 16);
        const bf16x8 bh1 = *(const bf16x8*)(w1 + ks * 16);

        acc0h = __builtin_amdgcn_mfma_f32_32x32x16_bf16(va0, bh0, acc0h, 0, 0, 0);
        acc0l = __builtin_amdgcn_mfma_f32_32x32x16_bf16(va1, bh0, acc0l, 0, 0, 0);
        acc1h = __builtin_amdgcn_mfma_f32_32x32x16_bf16(va0, bh1, acc1h, 0, 0, 0);
        acc1l = __builtin_amdgcn_mfma_f32_32x32x16_bf16(va1, bh1, acc1l, 0, 0, 0);
    }

    const floatx16 c0 = acc0h + acc0l;
    const floatx16 c1 = acc1h + acc1l;
    const int rbase = kh * 4;

    #pragma unroll
    for (int r = 0; r < 16; ++r) {
        const int row  = (r & 3) + 8 * (r >> 2) + rbase;   // 0..31
        const int grow = mt * 32 + row;                    // 0..799
        const int bi   = (grow >= SS) ? 1 : 0;
        const int rl   = grow - bi * SS;                   // t or s local
        #pragma unroll
        for (int u = 0; u < 2; ++u) {
            const float val  = u ? c1[r] : c0[r];
            const int   gcol = n0 + u * 32 + m;
            if (g == 0) {
                if (gcol < 512) {
                    ws[EAOFF + (size_t)grow * 512 + gcol] =
                        EXP2F(TWO_LOG2E * (val + bq[gcol]));
                } else {
                    const int d = gcol - 512;
                    out0[((size_t)(rl * BB + bi)) * 512 + d] = val + bout[d];
                }
            } else {
                if (gcol < 512) {
                    ws[EB4OFF + (size_t)((bi * 128 + (gcol >> 2)) * SS + rl) * 4
                       + (gcol & 3)] = EXP2F(TWO_LOG2E * val);
                } else {
                    ws[MOFF + (size_t)grow * 512 + (gcol - 512)] = val;
                }
            }
        }
    }
}

// ---------------------------------------------------------------------------
// K2a: raw score partials, t-QUAD x e-half. Grid (100 tq, 2 b, 2 eh) =
// 400 blocks, 512 thr. R9/R10 kernel with ONE change: unroll 4 -> 8
// (8 eb loads in flight; clean unconfounded pipeline-depth test — R3's
// version was confounded with 3 other changes). VGPR ~80, well under the
// residency cap at 3.1 waves/SIMD. Partials -> Sp[eh][b][t][512].
// ---------------------------------------------------------------------------
__global__ __launch_bounds__(512) void k2a_score(
    const float* __restrict__ ws, const float* __restrict__ v,
    float* __restrict__ sp)
{
    const int tq = blockIdx.x;            // 0..99
    const int b  = blockIdx.y;
    const int eh = blockIdx.z;            // 0..1
    const int t0 = tq * 4;
    const int tid = threadIdx.x;
    const int s   = tid;
    const int sidx = (s < SS) ? s : 0;

    const float* __restrict__ ea0p = ws + EAOFF + (size_t)(b * SS + t0) * 512;
    const float* __restrict__ ea1p = ea0p + 512;
    const float* __restrict__ ea2p = ea0p + 1024;
    const float* __restrict__ ea3p = ea0p + 1536;
    const float4* __restrict__ eb4 =
        (const float4*)(ws + EB4OFF) + (size_t)b * 128 * SS + sidx;

    float acc0 = 0.f, acc1 = 0.f, acc2 = 0.f, acc3 = 0.f;
    const int e4b = eh * 64;

#define QUAD(EAP, ACC)                                               \
    {                                                                \
        const float4 ea = *(const float4*)(EAP + e4 * 4);            \
        const float d0 = fmaf(ea.x, eb.x, 1.f);                      \
        const float d1 = fmaf(ea.y, eb.y, 1.f);                      \
        const float d2 = fmaf(ea.z, eb.z, 1.f);                      \
        const float d3 = fmaf(ea.w, eb.w, 1.f);                      \
        const float d01 = d0 * d1, d23 = d2 * d3;                    \
        const float n01 = fmaf(vv.x, d1, vv.y * d0);                 \
        const float n23 = fmaf(vv.z, d3, vv.w * d2);                 \
        const float num = fmaf(n01, d23, n23 * d01);                 \
        ACC = fmaf(num, RCPF(d01 * d23), ACC);                       \
    }

    #pragma unroll 8
    for (int e4 = e4b; e4 < e4b + 64; ++e4) {
        const float4 eb = eb4[(size_t)e4 * SS];
        const float4 vv = *(const float4*)(v + e4 * 4);   // uniform
        QUAD(ea0p, acc0)
        QUAD(ea1p, acc1)
        QUAD(ea2p, acc2)
        QUAD(ea3p, acc3)
    }
#undef QUAD

    const size_t base = ((size_t)(eh * 2 + b)) * 400;
    sp[(base + t0 + 0) * 512 + s] = acc0;
    sp[(base + t0 + 1) * 512 + s] = acc1;
    sp[(base + t0 + 2) * 512 + s] = acc2;
    sp[(base + t0 + 3) * 512 + s] = acc3;
}

// ---------------------------------------------------------------------------
// K2b: combine partials + softmax + context GEMV, t-QUAD. Grid (100,2) =
// 200 blocks, 512 thr. Changes vs R10:
//  (1) NO max-pass: |sc| = 2|sum v_e*r|, r in (0,1) => |sc| <= 2*sum|v_e|
//      ~ 36 (hard bound), exp(sc) <= 5e15, 400-term sum <= 2e18 << f32 max;
//      e^-36 ~ 2e-16 is normal (no underflow). Removes one shuffle+LDS
//      reduce round + one barrier. Masked lanes: p = 0 exactly.
//  (2) out0 values prefetched at kernel start (needed only at the end;
//      was an L3-latency read on the critical tail).
// Phase 2 identical to R10. Non-atomic: block owns its 4 (t,b) rows.
// ---------------------------------------------------------------------------
__global__ __launch_bounds__(512) void k2b_sm(
    const float* __restrict__ ws, const float* __restrict__ sp,
    const int* __restrict__ lens, float* __restrict__ out1,
    float* __restrict__ out0)
{
    const int tq = blockIdx.x;            // 0..99
    const int b  = blockIdx.y;
    const int t0 = tq * 4;
    const int tid = threadIdx.x;
    const int s   = tid;
    const int len  = lens[b];

    __shared__ float4 lal4[SS];           // align quad per s (6.4 KB)
    __shared__ float wreds[4][8];

    // prefetch out0 accumulator base values (used only in the epilogue)
    const int d = tid;                    // 0..511
    size_t oidx[4];
    float obase[4];
    #pragma unroll
    for (int j = 0; j < 4; ++j) {
        oidx[j]  = ((size_t)((t0 + j) * BB) + b) * DD + d;
        obase[j] = out0[oidx[j]];
    }

    const size_t b0 = ((size_t)(0 * 2 + b)) * 400;
    const size_t b1 = ((size_t)(1 * 2 + b)) * 400;
    float acc[4];
    #pragma unroll
    for (int j = 0; j < 4; ++j)
        acc[j] = sp[(b0 + t0 + j) * 512 + s] + sp[(b1 + t0 + j) * 512 + s];

    const int wid  = tid >> 6;            // 0..7
    const int lane = tid & 63;

    // p = exp(score) directly — no max subtraction needed (|sc| <= ~36)
    float p[4];
    #pragma unroll
    for (int j = 0; j < 4; ++j) {
        const bool ok = (s < SS) && (s < len) && (s != t0 + j);
        p[j] = ok ? __expf(-2.f * acc[j]) : 0.f;
    }

    float sv[4] = {p[0], p[1], p[2], p[3]};
    #pragma unroll
    for (int off = 32; off > 0; off >>= 1) {
        #pragma unroll
        for (int j = 0; j < 4; ++j)
            sv[j] += __shfl_xor(sv[j], off);
    }
    if (lane == 0) {
        #pragma unroll
        for (int j = 0; j < 4; ++j) wreds[j][wid] = sv[j];
    }
    __syncthreads();
    float inv[4];
    #pragma unroll
    for (int j = 0; j < 4; ++j) {
        float tot = wreds[j][0];
        #pragma unroll
        for (int w = 1; w < 8; ++w) tot += wreds[j][w];
        inv[j] = RCPF(tot);
    }

    if (s < SS) {
        float4 al;
        al.x = p[0] * inv[0];
        al.y = p[1] * inv[1];
        al.z = p[2] * inv[2];
        al.w = p[3] * inv[3];
        out1[((size_t)((t0 + 0) * BB) + b) * SS + s] = al.x;
        out1[((size_t)((t0 + 1) * BB) + b) * SS + s] = al.y;
        out1[((size_t)((t0 + 2) * BB) + b) * SS + s] = al.z;
        out1[((size_t)((t0 + 3) * BB) + b) * SS + s] = al.w;
        lal4[s] = al;
    }
    __syncthreads();

    // ---- phase 2: context GEMV, thread = d column, 4 t's per thread ----
    const float* __restrict__ Mb = ws + MOFF + (size_t)b * SS * DD;
    float c0 = 0.f, c1 = 0.f, c2 = 0.f, c3 = 0.f;
    #pragma unroll 16
    for (int sp2 = 0; sp2 < SS; ++sp2) {
        const float  mv = Mb[(size_t)sp2 * DD + d];
        const float4 la = lal4[sp2];                 // LDS broadcast
        c0 = fmaf(la.x, mv, c0);
        c1 = fmaf(la.y, mv, c1);
        c2 = fmaf(la.z, mv, c2);
        c3 = fmaf(la.w, mv, c3);
    }
    out0[oidx[0]] = obase[0] + c0;
    out0[oidx[1]] = obase[1] + c1;
    out0[oidx[2]] = obase[2] + c2;
    out0[oidx[3]] = obase[3] + c3;
}

// ---------------------------------------------------------------------------
extern "C" void kernel_launch(void* const* d_in, const int* in_sizes, int n_in,
                              void* d_out, int out_size, void* d_ws, size_t ws_size,
                              hipStream_t stream)
{
    const float* input = (const float*)d_in[0];
    const float* mbk   = (const float*)d_in[1];
    const int*   lens  = (const int*)d_in[2];
    const float* Wq    = (const float*)d_in[3];
    const float* bq    = (const float*)d_in[4];
    const float* Wc    = (const float*)d_in[5];
    const float* v     = (const float*)d_in[6];
    const float* Wout  = (const float*)d_in[7];
    const float* bout  = (const float*)d_in[8];

    float* out0 = (float*)d_out;               // [T,B,D] = 409600
    float* out1 = out0 + (size_t)BB * SS * DD; // [T,B,S] = 320000
    float* ws   = (float*)d_ws;
    unsigned short* x16 = (unsigned short*)(ws + XOFF);
    unsigned short* wt  = x16;                 // 2*1024*512 shorts
    unsigned short* ahi = x16 + 1048576;       // 2*800*512 shorts
    unsigned short* alo = ahi + 819200;
    float* sp = ws + SPOFF;                    // 819200 floats

    hipLaunchKernelGGL(k0_all, dim3(1824), dim3(256), 0, stream,
                       Wq, Wc, Wout, input, mbk, wt, ahi, alo);
    hipLaunchKernelGGL(k1_mfma, dim3(25, 16, 2), dim3(64), 0, stream,
                       ahi, alo, wt, bq, bout, ws, out0);
    hipLaunchKernelGGL(k2a_score, dim3(100, 2, 2), dim3(512), 0, stream,
                       ws, v, sp);
    hipLaunchKernelGGL(k2b_sm, dim3(100, 2), dim3(512), 0, stream,
                       ws, sp, lens, out1, out0);
}

// Round 12
// 139.551 us; speedup vs baseline: 1.0340x; 1.0340x over previous
//
#include <hip/hip_runtime.h>
#include <math.h>

// Problem constants (reference: B=2, S=T=400, D=512)
#define BB 2
#define SS 400
#define DD 512
#define TWO_LOG2E 2.8853900817779268f

#if __has_builtin(__builtin_amdgcn_exp2f)
#define EXP2F(x) __builtin_amdgcn_exp2f(x)
#else
#define EXP2F(x) exp2f(x)
#endif
#define RCPF(x) __builtin_amdgcn_rcpf(x)

// Workspace float layout:
//   Ea   [0,       409600) : exp2(2L*(input@Wq + bq))            [B,T,D]
//   M    [409600,  819200) : mb@Wout_top                         [B,S,D]
//   Eb4  [819200, 1228800) : exp2(2L*(mb@Wc)), packed [B][D/4][S][4]
//   X    [1228800, 2572288) : bf16 staging (shorts):
//        wt  [0,        1048576) : Wt [g][1024][512]
//        ahi [1048576,  1458176) : hi(A) [g][800][512]
//        alo [1458176,  1867776) : lo(A) [g][800][512]
//   Sp   [2572288, 3391488) : score partials [eh][b][t][512]
// out0 gets input@Wout_bot + bout from k1 (g0 cols>=512); k2b phase-2 adds
// align@M in-block (non-atomic, each (t,b) owned by exactly one block).
#define EAOFF 0
#define MOFF 409600
#define EB4OFF 819200
#define XOFF 1228800
#define SPOFF 2572288

typedef __bf16 bf16x8 __attribute__((ext_vector_type(8)));
typedef float floatx16 __attribute__((ext_vector_type(16)));

// ---------------------------------------------------------------------------
// K0: fused prep. Flat grid 1824 blocks, 256 thr.
//  gid < 1024: Wt[g][n][k] bf16 transpose-pack (32x32 LDS tiles).
//  gid >= 1024: two-term bf16 split of A (input / mb).
// ---------------------------------------------------------------------------
__global__ __launch_bounds__(256) void k0_all(
    const float* __restrict__ Wq, const float* __restrict__ Wc,
    const float* __restrict__ Wout, const float* __restrict__ input,
    const float* __restrict__ mbk, unsigned short* __restrict__ wt,
    unsigned short* __restrict__ ahi, unsigned short* __restrict__ alo)
{
    const int gid = blockIdx.x;
    if (gid < 1024) {
        const int g   = gid >> 9;
        const int rem = gid & 511;
        const int k0  = (rem & 15) * 32;
        const int n0  = (rem >> 4) * 32;

        __shared__ float tile[32][33];
        const int nn  = threadIdx.x & 31;
        const int kk0 = threadIdx.x >> 5;
        const int n   = n0 + nn;

        #pragma unroll
        for (int p = 0; p < 4; ++p) {
            const int k = k0 + kk0 + p * 8;
            float val;
            if (n0 < 512) val = (g ? Wc : Wq)[(size_t)k * 512 + n];
            else          val = Wout[((size_t)(g ? k : 512 + k)) * 512 + (n - 512)];
            tile[kk0 + p * 8][nn] = val;
        }
        __syncthreads();

        const int kc = threadIdx.x & 31;
        #pragma unroll
        for (int p = 0; p < 4; ++p) {
            const int nl = (threadIdx.x >> 5) + p * 8;
            const __bf16 h = (__bf16)tile[kc][nl];
            wt[((size_t)(g * 1024 + n0 + nl)) * 512 + k0 + kc] =
                __builtin_bit_cast(unsigned short, h);
        }
    } else {
        const int cid = gid - 1024;             // 0..799
        const int g   = (cid >= 400) ? 1 : 0;
        const int i4  = (cid - g * 400) * 256 + threadIdx.x;   // 0..102399
        const float4 a = ((const float4*)(g ? mbk : input))[i4];
        ushort4 h, l;
        #pragma unroll
        for (int j = 0; j < 4; ++j) {
            const float av = (&a.x)[j];
            const __bf16 hh = (__bf16)av;
            (&h.x)[j] = __builtin_bit_cast(unsigned short, hh);
            const __bf16 ll = (__bf16)(av - (float)hh);
            (&l.x)[j] = __builtin_bit_cast(unsigned short, ll);
        }
        ((ushort4*)(ahi + (size_t)g * 409600))[i4] = h;
        ((ushort4*)(alo + (size_t)g * 409600))[i4] = l;
    }
}

// ---------------------------------------------------------------------------
// K1: two merged GEMMs (800 x 1024 x 512) via MFMA, pre-split bf16 A.
// Grid (25 mtiles, 16 npairs, 2 g), 64 thr = 1 wave; wave tile 32x64.
// C/D: col=lane&31, row=(reg&3)+8*(reg>>2)+4*(lane>>5).
// Fused epilogues by n-range/g: Ea, out0(=P+bout), Eb4 scatter, M.
// ---------------------------------------------------------------------------
__global__ __launch_bounds__(64) void k1_mfma(
    const unsigned short* __restrict__ ahi, const unsigned short* __restrict__ alo,
    const unsigned short* __restrict__ wt, const float* __restrict__ bq,
    const float* __restrict__ bout, float* __restrict__ ws,
    float* __restrict__ out0)
{
    const int lane = threadIdx.x;
    const int mt   = blockIdx.x;          // 0..24
    const int np   = blockIdx.y;          // 0..15
    const int g    = blockIdx.z;
    const int m    = lane & 31;
    const int kh   = lane >> 5;
    const int n0   = np * 64;

    const size_t arow = ((size_t)g * 800 + mt * 32 + m) * 512 + kh * 8;
    const unsigned short* __restrict__ ah = ahi + arow;
    const unsigned short* __restrict__ al = alo + arow;
    const unsigned short* __restrict__ w0 =
        wt + ((size_t)(g * 1024 + n0 + m)) * 512 + kh * 8;
    const unsigned short* __restrict__ w1 = w0 + (size_t)32 * 512;

    floatx16 acc0h, acc0l, acc1h, acc1l;
    #pragma unroll
    for (int i = 0; i < 16; ++i) { acc0h[i] = 0.f; acc0l[i] = 0.f;
                                   acc1h[i] = 0.f; acc1l[i] = 0.f; }

    #pragma unroll 4
    for (int ks = 0; ks < 32; ++ks) {
        const bf16x8 va0 = *(const bf16x8*)(ah + ks * 16);
        const bf16x8 va1 = *(const bf16x8*)(al + ks * 16);
        const bf16x8 bh0 = *(const bf16x8*)(w0 + ks * 16);
        const bf16x8 bh1 = *(const bf16x8*)(w1 + ks * 16);

        acc0h = __builtin_amdgcn_mfma_f32_32x32x16_bf16(va0, bh0, acc0h, 0, 0, 0);
        acc0l = __builtin_amdgcn_mfma_f32_32x32x16_bf16(va1, bh0, acc0l, 0, 0, 0);
        acc1h = __builtin_amdgcn_mfma_f32_32x32x16_bf16(va0, bh1, acc1h, 0, 0, 0);
        acc1l = __builtin_amdgcn_mfma_f32_32x32x16_bf16(va1, bh1, acc1l, 0, 0, 0);
    }

    const floatx16 c0 = acc0h + acc0l;
    const floatx16 c1 = acc1h + acc1l;
    const int rbase = kh * 4;

    #pragma unroll
    for (int r = 0; r < 16; ++r) {
        const int row  = (r & 3) + 8 * (r >> 2) + rbase;   // 0..31
        const int grow = mt * 32 + row;                    // 0..799
        const int bi   = (grow >= SS) ? 1 : 0;
        const int rl   = grow - bi * SS;                   // t or s local
        #pragma unroll
        for (int u = 0; u < 2; ++u) {
            const float val  = u ? c1[r] : c0[r];
            const int   gcol = n0 + u * 32 + m;
            if (g == 0) {
                if (gcol < 512) {
                    ws[EAOFF + (size_t)grow * 512 + gcol] =
                        EXP2F(TWO_LOG2E * (val + bq[gcol]));
                } else {
                    const int d = gcol - 512;
                    out0[((size_t)(rl * BB + bi)) * 512 + d] = val + bout[d];
                }
            } else {
                if (gcol < 512) {
                    ws[EB4OFF + (size_t)((bi * 128 + (gcol >> 2)) * SS + rl) * 4
                       + (gcol & 3)] = EXP2F(TWO_LOG2E * val);
                } else {
                    ws[MOFF + (size_t)grow * 512 + (gcol - 512)] = val;
                }
            }
        }
    }
}

// ---------------------------------------------------------------------------
// K2a: raw score partials, t-QUAD x e-half. Grid (100 tq, 2 b, 2 eh) =
// 400 blocks, 512 thr. At chip VALU floor (~12 us). unroll 4 (R11's 8
// regressed). Partials -> Sp[eh][b][t][512].
// ---------------------------------------------------------------------------
__global__ __launch_bounds__(512) void k2a_score(
    const float* __restrict__ ws, const float* __restrict__ v,
    float* __restrict__ sp)
{
    const int tq = blockIdx.x;            // 0..99
    const int b  = blockIdx.y;
    const int eh = blockIdx.z;            // 0..1
    const int t0 = tq * 4;
    const int tid = threadIdx.x;
    const int s   = tid;
    const int sidx = (s < SS) ? s : 0;

    const float* __restrict__ ea0p = ws + EAOFF + (size_t)(b * SS + t0) * 512;
    const float* __restrict__ ea1p = ea0p + 512;
    const float* __restrict__ ea2p = ea0p + 1024;
    const float* __restrict__ ea3p = ea0p + 1536;
    const float4* __restrict__ eb4 =
        (const float4*)(ws + EB4OFF) + (size_t)b * 128 * SS + sidx;

    float acc0 = 0.f, acc1 = 0.f, acc2 = 0.f, acc3 = 0.f;
    const int e4b = eh * 64;

#define QUAD(EAP, ACC)                                               \
    {                                                                \
        const float4 ea = *(const float4*)(EAP + e4 * 4);            \
        const float d0 = fmaf(ea.x, eb.x, 1.f);                      \
        const float d1 = fmaf(ea.y, eb.y, 1.f);                      \
        const float d2 = fmaf(ea.z, eb.z, 1.f);                      \
        const float d3 = fmaf(ea.w, eb.w, 1.f);                      \
        const float d01 = d0 * d1, d23 = d2 * d3;                    \
        const float n01 = fmaf(vv.x, d1, vv.y * d0);                 \
        const float n23 = fmaf(vv.z, d3, vv.w * d2);                 \
        const float num = fmaf(n01, d23, n23 * d01);                 \
        ACC = fmaf(num, RCPF(d01 * d23), ACC);                       \
    }

    #pragma unroll 4
    for (int e4 = e4b; e4 < e4b + 64; ++e4) {
        const float4 eb = eb4[(size_t)e4 * SS];
        const float4 vv = *(const float4*)(v + e4 * 4);   // uniform
        QUAD(ea0p, acc0)
        QUAD(ea1p, acc1)
        QUAD(ea2p, acc2)
        QUAD(ea3p, acc3)
    }
#undef QUAD

    const size_t base = ((size_t)(eh * 2 + b)) * 400;
    sp[(base + t0 + 0) * 512 + s] = acc0;
    sp[(base + t0 + 1) * 512 + s] = acc1;
    sp[(base + t0 + 2) * 512 + s] = acc2;
    sp[(base + t0 + 3) * 512 + s] = acc3;
}

// ---------------------------------------------------------------------------
// K2b: combine partials + softmax + context GEMV, t-QUAD. Grid (100,2) =
// 200 blocks, 512 thr. 4 t's per block -> M re-read 100x per b (164 MB L2).
// Softmax x4 with max-pass (R11's removal bought nothing). Phase 2:
// thread = d, 4 acc chains, unroll 16. Non-atomic: block owns its 4 rows.
// ---------------------------------------------------------------------------
__global__ __launch_bounds__(512) void k2b_sm(
    const float* __restrict__ ws, const float* __restrict__ sp,
    const int* __restrict__ lens, float* __restrict__ out1,
    float* __restrict__ out0)
{
    const int tq = blockIdx.x;            // 0..99
    const int b  = blockIdx.y;
    const int t0 = tq * 4;
    const int tid = threadIdx.x;
    const int s   = tid;
    const int len  = lens[b];

    __shared__ float4 lal4[SS];           // align quad per s (6.4 KB)
    __shared__ float wredm[4][8], wreds[4][8];

    const size_t b0 = ((size_t)(0 * 2 + b)) * 400;
    const size_t b1 = ((size_t)(1 * 2 + b)) * 400;
    float acc[4];
    #pragma unroll
    for (int j = 0; j < 4; ++j)
        acc[j] = sp[(b0 + t0 + j) * 512 + s] + sp[(b1 + t0 + j) * 512 + s];

    const int wid  = tid >> 6;            // 0..7
    const int lane = tid & 63;

    bool  ok[4];
    float sc[4];
    #pragma unroll
    for (int j = 0; j < 4; ++j) {
        ok[j] = (s < SS) && (s < len) && (s != t0 + j);
        sc[j] = ok[j] ? -2.f * acc[j] : -INFINITY;
    }

    float m[4] = {sc[0], sc[1], sc[2], sc[3]};
    #pragma unroll
    for (int off = 32; off > 0; off >>= 1) {
        #pragma unroll
        for (int j = 0; j < 4; ++j)
            m[j] = fmaxf(m[j], __shfl_xor(m[j], off));
    }
    if (lane == 0) {
        #pragma unroll
        for (int j = 0; j < 4; ++j) wredm[j][wid] = m[j];
    }
    __syncthreads();
    float mx[4];
    #pragma unroll
    for (int j = 0; j < 4; ++j) {
        mx[j] = wredm[j][0];
        #pragma unroll
        for (int w = 1; w < 8; ++w) mx[j] = fmaxf(mx[j], wredm[j][w]);
    }
    __syncthreads();

    float p[4];
    #pragma unroll
    for (int j = 0; j < 4; ++j)
        p[j] = ok[j] ? __expf(sc[j] - mx[j]) : 0.f;
    float sv[4] = {p[0], p[1], p[2], p[3]};
    #pragma unroll
    for (int off = 32; off > 0; off >>= 1) {
        #pragma unroll
        for (int j = 0; j < 4; ++j)
            sv[j] += __shfl_xor(sv[j], off);
    }
    if (lane == 0) {
        #pragma unroll
        for (int j = 0; j < 4; ++j) wreds[j][wid] = sv[j];
    }
    __syncthreads();
    float inv[4];
    #pragma unroll
    for (int j = 0; j < 4; ++j) {
        float tot = wreds[j][0];
        #pragma unroll
        for (int w = 1; w < 8; ++w) tot += wreds[j][w];
        inv[j] = RCPF(tot);
    }

    if (s < SS) {
        float4 al;
        al.x = p[0] * inv[0];
        al.y = p[1] * inv[1];
        al.z = p[2] * inv[2];
        al.w = p[3] * inv[3];
        out1[((size_t)((t0 + 0) * BB) + b) * SS + s] = al.x;
        out1[((size_t)((t0 + 1) * BB) + b) * SS + s] = al.y;
        out1[((size_t)((t0 + 2) * BB) + b) * SS + s] = al.z;
        out1[((size_t)((t0 + 3) * BB) + b) * SS + s] = al.w;
        lal4[s] = al;
    }
    __syncthreads();

    // ---- phase 2: context GEMV, thread = d column, 4 t's per thread ----
    const float* __restrict__ Mb = ws + MOFF + (size_t)b * SS * DD;
    const int d = tid;                    // 0..511
    float c0 = 0.f, c1 = 0.f, c2 = 0.f, c3 = 0.f;
    #pragma unroll 16
    for (int sp2 = 0; sp2 < SS; ++sp2) {
        const float  mv = Mb[(size_t)sp2 * DD + d];
        const float4 la = lal4[sp2];                 // LDS broadcast
        c0 = fmaf(la.x, mv, c0);
        c1 = fmaf(la.y, mv, c1);
        c2 = fmaf(la.z, mv, c2);
        c3 = fmaf(la.w, mv, c3);
    }
    out0[((size_t)((t0 + 0) * BB) + b) * DD + d] += c0;
    out0[((size_t)((t0 + 1) * BB) + b) * DD + d] += c1;
    out0[((size_t)((t0 + 2) * BB) + b) * DD + d] += c2;
    out0[((size_t)((t0 + 3) * BB) + b) * DD + d] += c3;
}

// ---------------------------------------------------------------------------
extern "C" void kernel_launch(void* const* d_in, const int* in_sizes, int n_in,
                              void* d_out, int out_size, void* d_ws, size_t ws_size,
                              hipStream_t stream)
{
    const float* input = (const float*)d_in[0];
    const float* mbk   = (const float*)d_in[1];
    const int*   lens  = (const int*)d_in[2];
    const float* Wq    = (const float*)d_in[3];
    const float* bq    = (const float*)d_in[4];
    const float* Wc    = (const float*)d_in[5];
    const float* v     = (const float*)d_in[6];
    const float* Wout  = (const float*)d_in[7];
    const float* bout  = (const float*)d_in[8];

    float* out0 = (float*)d_out;               // [T,B,D] = 409600
    float* out1 = out0 + (size_t)BB * SS * DD; // [T,B,S] = 320000
    float* ws   = (float*)d_ws;
    unsigned short* x16 = (unsigned short*)(ws + XOFF);
    unsigned short* wt  = x16;                 // 2*1024*512 shorts
    unsigned short* ahi = x16 + 1048576;       // 2*800*512 shorts
    unsigned short* alo = ahi + 819200;
    float* sp = ws + SPOFF;                    // 819200 floats

    hipLaunchKernelGGL(k0_all, dim3(1824), dim3(256), 0, stream,
                       Wq, Wc, Wout, input, mbk, wt, ahi, alo);
    hipLaunchKernelGGL(k1_mfma, dim3(25, 16, 2), dim3(64), 0, stream,
                       ahi, alo, wt, bq, bout, ws, out0);
    hipLaunchKernelGGL(k2a_score, dim3(100, 2, 2), dim3(512), 0, stream,
                       ws, v, sp);
    hipLaunchKernelGGL(k2b_sm, dim3(100, 2), dim3(512), 0, stream,
                       ws, sp, lens, out1, out0);
}